// Round 13
// baseline (130.188 us; speedup 1.0000x reference)
//
#include <hip/hip_runtime.h>
#include <math.h>

#define PCNT 2048
#define CDIM 512
#define CAP_B (PCNT * 9)        // worst-case entries/batch (box spans <=3x3 cells)

// ------------------------------------------------------------------
// K1 "front": blocks [0, 8B) = prep+scatter per (b, octant);
//             blocks [8B, 8B+rows/16) = gemv+softmax.
// (R12-proven) Block-private scatter: each block recomputes seeds and
// per-(cell,octant) counts, derives disjoint slot ranges, scatters its
// own 256 boxes. Also zeroes keys/doneCnt/batchDone.
// ------------------------------------------------------------------
__global__ __launch_bounds__(256) void k_front(
    const float* __restrict__ in, const float* __restrict__ W,
    const float* __restrict__ bias, float* __restrict__ out,
    const float* __restrict__ ps, const float* __restrict__ rois,
    unsigned long long* __restrict__ keys, int nkeys,
    int* __restrict__ cellCnt, float4* __restrict__ roisE,
    unsigned* __restrict__ metaU, unsigned* __restrict__ doneCnt,
    unsigned* __restrict__ batchDone,
    int scatterBlocks, int B)
{
    __shared__ float4 w_lds[512];
    __shared__ float  sval[256];
    __shared__ int    sidx[256];
    __shared__ int    scnt[256];
    __shared__ int    cnt512[512];     // [cell][octant]
    __shared__ int    cur64[64];
    __shared__ int    amaxS[3], cntS[3];
    int tid = threadIdx.x;
    int bid = blockIdx.x;

    if (bid < scatterBlocks) {
        int b = bid >> 3, oct = bid & 7;
        int share = nkeys / scatterBlocks;
        for (int t = tid; t < share; t += 256) keys[bid * share + t] = 0ull;
        if (bid == 0) {
            if (tid == 0) *doneCnt = 0u;
            if (tid < B) batchDone[tid * 16] = 0u;
        }

        const float4* psb = (const float4*)ps + (size_t)b * PCNT;
        const float4* rb  = (const float4*)rois + (size_t)b * PCNT;

        // ---- seeds: 3 classes, one ps scan ----
        float bv0 = -1e30f, bv1 = -1e30f, bv2 = -1e30f;
        int bi0 = 0, bi1 = 0, bi2 = 0, c0 = 0, c1 = 0, c2 = 0;
#pragma unroll
        for (int t = 0; t < PCNT / 256; ++t) {
            int j = tid + t * 256;
            float4 pv = psb[j];
            if (pv.x > 0.5f) c0++;
            if (pv.x > bv0) { bv0 = pv.x; bi0 = j; }
            if (pv.y > 0.5f) c1++;
            if (pv.y > bv1) { bv1 = pv.y; bi1 = j; }
            if (pv.z > 0.5f) c2++;
            if (pv.z > bv2) { bv2 = pv.z; bi2 = j; }
        }
#pragma unroll
        for (int c = 0; c < 3; ++c) {
            sval[tid] = (c == 0) ? bv0 : (c == 1) ? bv1 : bv2;
            sidx[tid] = (c == 0) ? bi0 : (c == 1) ? bi1 : bi2;
            scnt[tid] = (c == 0) ? c0  : (c == 1) ? c1  : c2;
            __syncthreads();
            for (int s = 128; s > 0; s >>= 1) {
                if (tid < s) {
                    float v2 = sval[tid + s]; int i2 = sidx[tid + s];
                    if (v2 > sval[tid] || (v2 == sval[tid] && i2 < sidx[tid])) { sval[tid] = v2; sidx[tid] = i2; }
                    scnt[tid] += scnt[tid + s];
                }
                __syncthreads();
            }
            if (tid == 0) { amaxS[c] = sidx[0]; cntS[c] = scnt[0]; }
            __syncthreads();
        }

        // ---- counts per (cell, octant) ----
        cnt512[tid] = 0; cnt512[tid + 256] = 0;
        __syncthreads();
#pragma unroll
        for (int t = 0; t < PCNT / 256; ++t) {
            int j = tid + t * 256;
            float4 q = rb[j];
            int jo = j >> 8;
            int cx0 = min(((int)q.x) >> 7, 7), cx1 = min(((int)q.z) >> 7, 7);
            int cy0 = min(((int)q.y) >> 7, 7), cy1 = min(((int)q.w) >> 7, 7);
            for (int cy = cy0; cy <= cy1; ++cy)
                for (int cx = cx0; cx <= cx1; ++cx)
                    atomicAdd(&cnt512[(cy * 8 + cx) * 8 + jo], 1);
        }
        __syncthreads();
        if (tid < 64) {
            int tot = 0, pre = 0;
#pragma unroll
            for (int o = 0; o < 8; ++o) {
                int v = cnt512[tid * 8 + o];
                if (o < oct) pre += v;
                tot += v;
            }
            int incl = tot;
#pragma unroll
            for (int d = 1; d < 64; d <<= 1) {
                int v = __shfl_up(incl, d, 64);
                if (tid >= d) incl += v;
            }
            cur64[tid] = (incl - tot) + pre;
            cellCnt[b * 64 + tid] = tot;
        }
        __syncthreads();
        {
            int j = oct * 256 + tid;
            float4 q  = rb[j];
            float4 pv = psb[j];
            unsigned m0 = ((cntS[0] <= 1) ? (j == amaxS[0]) : (pv.x > 0.5f)) ? 0x10000u : 0u;
            unsigned m1 = ((cntS[1] <= 1) ? (j == amaxS[1]) : (pv.y > 0.5f)) ? 0x20000u : 0u;
            unsigned m2 = ((cntS[2] <= 1) ? (j == amaxS[2]) : (pv.z > 0.5f)) ? 0x40000u : 0u;
            unsigned meta = (unsigned)j | m0 | m1 | m2;
            int cx0 = min(((int)q.x) >> 7, 7), cx1 = min(((int)q.z) >> 7, 7);
            int cy0 = min(((int)q.y) >> 7, 7), cy1 = min(((int)q.w) >> 7, 7);
            for (int cy = cy0; cy <= cy1; ++cy)
                for (int cx = cx0; cx <= cx1; ++cx) {
                    int e = atomicAdd(&cur64[cy * 8 + cx], 1);
                    size_t pos = (size_t)b * CAP_B + e;
                    roisE[pos] = q;
                    metaU[pos] = meta;
                }
        }
    } else {
        // ============ gemv + softmax ============
        int gbid = bid - scatterBlocks;
        if (scatterBlocks == 0) {
            int gid = gbid * 256 + tid;
            if (gid < nkeys) keys[gid] = 0ull;
            if (gid == 0) *doneCnt = 0u;
        }
        const float4* W4 = (const float4*)W;   // [c*128 + q], q = m*16+k
        for (int e = tid; e < 512; e += 256) {
            int k = e & 15, c = (e >> 4) & 3, m = e >> 6;
            w_lds[e] = W4[c * 128 + m * 16 + k];
        }
        __syncthreads();
        int row = gbid * 16 + (tid >> 4);
        int k   = tid & 15;
        const float4* ip = (const float4*)(in + (size_t)row * CDIM);
        float4 v[8];
#pragma unroll
        for (int m = 0; m < 8; ++m) v[m] = ip[m * 16 + k];
        float a0 = 0.f, a1 = 0.f, a2 = 0.f, a3 = 0.f;
#pragma unroll
        for (int m = 0; m < 8; ++m) {
            float4 w0 = w_lds[(m * 4 + 0) * 16 + k];
            float4 w1 = w_lds[(m * 4 + 1) * 16 + k];
            float4 w2 = w_lds[(m * 4 + 2) * 16 + k];
            float4 w3 = w_lds[(m * 4 + 3) * 16 + k];
            a0 += v[m].x*w0.x + v[m].y*w0.y + v[m].z*w0.z + v[m].w*w0.w;
            a1 += v[m].x*w1.x + v[m].y*w1.y + v[m].z*w1.z + v[m].w*w1.w;
            a2 += v[m].x*w2.x + v[m].y*w2.y + v[m].z*w2.z + v[m].w*w2.w;
            a3 += v[m].x*w3.x + v[m].y*w3.y + v[m].z*w3.z + v[m].w*w3.w;
        }
#pragma unroll
        for (int off = 1; off < 16; off <<= 1) {
            a0 += __shfl_xor(a0, off, 64);
            a1 += __shfl_xor(a1, off, 64);
            a2 += __shfl_xor(a2, off, 64);
            a3 += __shfl_xor(a3, off, 64);
        }
        if (k == 0) {
            a0 += bias[0]; a1 += bias[1]; a2 += bias[2]; a3 += bias[3];
            float m = fmaxf(fmaxf(a0, a1), fmaxf(a2, a3));
            float e0 = expf(a0 - m), e1 = expf(a1 - m), e2 = expf(a2 - m), e3 = expf(a3 - m);
            float inv = 1.f / (e0 + e1 + e2 + e3);
            ((float4*)out)[row] = make_float4(e0 * inv, e1 * inv, e2 * inv, e3 * inv);
        }
    }
}

// ------------------------------------------------------------------
// K2 fused: blocks [0, B*64) = assignment (R12-proven k_assign5);
// each increments batchDone[b] (release) when done. Blocks
// [B*64, B*64+B*8) = finalize: poll own batch's counter (acquire,
// s_sleep backoff), then per-row finalize + partials + last-block
// loss reduce. Producers have no deps -> no deadlock if co-resident.
// ------------------------------------------------------------------
__global__ __launch_bounds__(256) void k_assign_fin(
    const int* __restrict__ cellCnt,
    const float4* __restrict__ roisE, const unsigned* __restrict__ metaU,
    unsigned long long* __restrict__ keys,
    const float* __restrict__ ps, const float* __restrict__ labels,
    const float* __restrict__ logit,
    float* __restrict__ partials, unsigned* __restrict__ doneCnt,
    unsigned* __restrict__ batchDone, float* __restrict__ out_loss,
    int B, float invB)
{
    int tid = threadIdx.x;
    int bid = blockIdx.x;
    int assignBlocks = B * 64;
    int lane = tid & 63;

    if (bid < assignBlocks) {
        // ================= assignment =================
        int b = bid >> 6;
        int cnt = cellCnt[b * 64 + lane];
        int einc = cnt;
#pragma unroll
        for (int d = 1; d < 64; d <<= 1) {
            int v = __shfl_up(einc, d, 64);
            if (lane >= d) einc += v;
        }
        int eexc = einc - cnt;
        int grp = (cnt + 7) >> 3;
        int ginc = grp;
#pragma unroll
        for (int d = 1; d < 64; d <<= 1) {
            int v = __shfl_up(ginc, d, 64);
            if (lane >= d) ginc += v;
        }
        int gexc = ginc - grp;
        int total = __shfl(ginc, 63, 64);
        int widx = ((bid & 63) << 2) + (tid >> 6);
        int il = lane >> 3, jl = lane & 7;

        for (int idx = widx; idx < total; idx += 256) {
            unsigned long long msk = __ballot(idx >= gexc && idx < ginc);
            int cell = __ffsll((unsigned long long)msk) - 1;
            int g = idx - __shfl(gexc, cell, 64);
            int n = __shfl(cnt, cell, 64);
            size_t base = (size_t)b * CAP_B + __shfl(eexc, cell, 64);
            int ie = g * 8 + il;
            bool ivalid = ie < n;
            int iload = ivalid ? ie : 0;
            float4 r = roisE[base + iload];
            int i_prop = (int)(metaU[base + iload] & 0xFFFFu);
            float areaA = (r.z - r.x) * (r.w - r.y);

            unsigned long long best0 = 0, best1 = 0, best2 = 0;
            for (int e = jl; e < n; e += 8) {
                float4 q = roisE[base + e];
                unsigned mu = metaU[base + e];
                float lx = fmaxf(r.x, q.x), ly = fmaxf(r.y, q.y);
                float rx = fminf(r.z, q.z), ry = fminf(r.w, q.w);
                float ww = fmaxf(rx - lx, 0.f);
                float hh = fmaxf(ry - ly, 0.f);
                float inter = ww * hh;
                float areaB = (q.z - q.x) * (q.w - q.y);
                float u = (areaA + areaB) - inter;
                float ioup1 = fmaf(inter, __builtin_amdgcn_rcpf(u), 1.0f);
                float iour = ioup1 - 1.0f;
                unsigned lo = 0x7FFFFFFFu - (mu & 0xFFFFu);
                float t0 = (mu & 0x10000u) ? iour : 0.f;
                float t1 = (mu & 0x20000u) ? iour : 0.f;
                float t2 = (mu & 0x40000u) ? iour : 0.f;
                unsigned long long k0 = ((unsigned long long)(unsigned)__float_as_int(t0) << 32) | lo;
                unsigned long long k1 = ((unsigned long long)(unsigned)__float_as_int(t1) << 32) | lo;
                unsigned long long k2 = ((unsigned long long)(unsigned)__float_as_int(t2) << 32) | lo;
                if (k0 > best0) best0 = k0;
                if (k1 > best1) best1 = k1;
                if (k2 > best2) best2 = k2;
            }
#pragma unroll
            for (int off = 1; off < 8; off <<= 1) {
                unsigned long long o;
                o = __shfl_xor(best0, off, 64); if (o > best0) best0 = o;
                o = __shfl_xor(best1, off, 64); if (o > best1) best1 = o;
                o = __shfl_xor(best2, off, 64); if (o > best2) best2 = o;
            }
            if (jl == 0 && ivalid) {
                size_t kb = ((size_t)b * PCNT + i_prop) * 3;
                if ((unsigned)(best0 >> 32) >= 0x3F000000u) atomicMax(&keys[kb + 0], best0);
                if ((unsigned)(best1 >> 32) >= 0x3F000000u) atomicMax(&keys[kb + 1], best1);
                if ((unsigned)(best2 >> 32) >= 0x3F000000u) atomicMax(&keys[kb + 2], best2);
            }
        }
        // signal completion for this batch
        __syncthreads();
        if (tid == 0) {
            __threadfence();
            __hip_atomic_fetch_add(&batchDone[b * 16], 1u,
                                   __ATOMIC_RELEASE, __HIP_MEMORY_SCOPE_AGENT);
        }
    } else {
        // ================= finalize =================
        int f = bid - assignBlocks;            // 0 .. B*8-1
        int b = f >> 3;
        if (tid == 0) {
            while (__hip_atomic_load(&batchDone[b * 16], __ATOMIC_ACQUIRE,
                                     __HIP_MEMORY_SCOPE_AGENT) < 64u)
                __builtin_amdgcn_s_sleep(32);
        }
        __syncthreads();
        __threadfence();

        int row = f * 256 + tid;
        float vals[8] = {0.f, 0.f, 0.f, 0.f, 0.f, 0.f, 0.f, 0.f};
        {
            float I = -1.f; int cls = 3; float wv = 1.f;
#pragma unroll
            for (int c = 0; c < 3; ++c) {
                unsigned long long key = keys[(size_t)row * 3 + c];
                float lab = labels[b * 4 + c];
                if (key != 0ull && lab > 0.f) {
                    float t = __uint_as_float((unsigned)(key >> 32));
                    if (t >= 0.5f && t > I) {
                        int j = 0x7FFFFFFF - (int)(key & 0xFFFFFFFFull);
                        I = t; cls = c;
                        wv = ps[((size_t)b * PCNT + j) * 4 + c];
                    }
                }
            }
            float4 lg = ((const float4*)logit)[row];
            float l = (cls == 0) ? lg.x : (cls == 1) ? lg.y : (cls == 2) ? lg.z : lg.w;
            float p = fminf(fmaxf(l, 1e-7f), 1.f - 1e-7f);
            float om = 1.f - p;
            float fl = -logf(p) * om * om;
            float lab = (cls == 3) ? 1.f : labels[b * 4 + cls];
            float wu = 10.f * expf(l) * (1.f - lab) + lab;
            float contrib = wv * fl * wu;
            vals[cls]     = contrib;
            vals[cls + 4] = 1.f;
        }
#pragma unroll
        for (int comp = 0; comp < 8; ++comp) {
#pragma unroll
            for (int off = 1; off < 64; off <<= 1)
                vals[comp] += __shfl_xor(vals[comp], off, 64);
        }
        __shared__ float wred[4][8];
        __shared__ bool lastBlk;
        int wave = tid >> 6;
        if (lane == 0) {
#pragma unroll
            for (int comp = 0; comp < 8; ++comp) wred[wave][comp] = vals[comp];
        }
        __syncthreads();
        int nfin = B * 8;
        if (tid < 8) {
            partials[f * 8 + tid] =
                wred[0][tid] + wred[1][tid] + wred[2][tid] + wred[3][tid];
            __threadfence();
        }
        __syncthreads();
        if (tid == 0) {
            unsigned old = atomicAdd(doneCnt, 1u);
            lastBlk = (old == (unsigned)(nfin - 1));
        }
        __syncthreads();
        if (lastBlk) {
            __threadfence();
            __shared__ float red8[8][32];
            int c = tid & 7, i = tid >> 3;   // i in [0,32)
            float s = 0.f;
            for (int kb = i; kb < nfin; kb += 32) s += partials[kb * 8 + c];
            red8[c][i] = s;
            __syncthreads();
            for (int st = 16; st > 0; st >>= 1) {
                if (i < st) red8[c][i] += red8[c][i + st];
                __syncthreads();
            }
            if (tid == 0) {
                float loss = 0.f;
#pragma unroll
                for (int cc = 0; cc < 4; ++cc)
                    loss += red8[cc][0] / (red8[cc + 4][0] + 1e-7f);
                *out_loss = loss * invB;
            }
        }
    }
}

// ------------------------------------------------------------------
// Fallback path (ws too small): seeds + full-scan assign + finalize.
// ------------------------------------------------------------------
__global__ __launch_bounds__(256) void k_seeds(
    const float* __restrict__ ps, int* __restrict__ seedsCnt,
    int* __restrict__ seedsAmax)
{
    int b = blockIdx.x / 3, c = blockIdx.x % 3;
    int tid = threadIdx.x;
    __shared__ float sval[256];
    __shared__ int   sidx[256];
    __shared__ int   scnt[256];
    float bestv = -1e30f; int besti = 0; int cnt = 0;
#pragma unroll
    for (int t = 0; t < PCNT / 256; ++t) {
        int j = tid + t * 256;
        float v = ps[((size_t)b * PCNT + j) * 4 + c];
        if (v > 0.5f) cnt++;
        if (v > bestv) { bestv = v; besti = j; }
    }
    sval[tid] = bestv; sidx[tid] = besti; scnt[tid] = cnt;
    __syncthreads();
    for (int s = 128; s > 0; s >>= 1) {
        if (tid < s) {
            float v2 = sval[tid + s]; int i2 = sidx[tid + s];
            if (v2 > sval[tid] || (v2 == sval[tid] && i2 < sidx[tid])) { sval[tid] = v2; sidx[tid] = i2; }
            scnt[tid] += scnt[tid + s];
        }
        __syncthreads();
    }
    if (tid == 0) { seedsCnt[blockIdx.x] = scnt[0]; seedsAmax[blockIdx.x] = sidx[0]; }
}

__global__ __launch_bounds__(256) void k_assign_fallback(
    const float* __restrict__ rois, const float* __restrict__ ps,
    const int* __restrict__ seedsCnt, const int* __restrict__ seedsAmax,
    unsigned long long* __restrict__ keys)
{
    int tid = threadIdx.x;
    int item = blockIdx.x * 4 + (tid >> 6);
    int b = item >> 8;
    int g = item & 255;
    int lane = tid & 63, il = lane >> 3, jl = lane & 7;
    int ie = g * 8 + il;
    const float4* rb = (const float4*)rois + (size_t)b * PCNT;
    const float4* pb = (const float4*)ps + (size_t)b * PCNT;
    float4 r = rb[ie];
    float areaA = (r.z - r.x) * (r.w - r.y);
    int c0 = seedsCnt[b*3+0], a0 = seedsAmax[b*3+0];
    int c1 = seedsCnt[b*3+1], a1 = seedsAmax[b*3+1];
    int c2 = seedsCnt[b*3+2], a2 = seedsAmax[b*3+2];

    unsigned long long best0 = 0, best1 = 0, best2 = 0;
    for (int e = jl; e < PCNT; e += 8) {
        float4 q = rb[e];
        float4 pv = pb[e];
        bool m0 = (c0 <= 1) ? (e == a0) : (pv.x > 0.5f);
        bool m1 = (c1 <= 1) ? (e == a1) : (pv.y > 0.5f);
        bool m2 = (c2 <= 1) ? (e == a2) : (pv.z > 0.5f);
        float lx = fmaxf(r.x, q.x), ly = fmaxf(r.y, q.y);
        float rx = fminf(r.z, q.z), ry = fminf(r.w, q.w);
        float ww = fmaxf(rx - lx, 0.f);
        float hh = fmaxf(ry - ly, 0.f);
        float inter = ww * hh;
        float areaB = (q.z - q.x) * (q.w - q.y);
        float u = (areaA + areaB) - inter;
        float ioup1 = fmaf(inter, __builtin_amdgcn_rcpf(u), 1.0f);
        float iour = ioup1 - 1.0f;
        unsigned lo = 0x7FFFFFFFu - (unsigned)e;
        float t0 = m0 ? iour : 0.f;
        float t1 = m1 ? iour : 0.f;
        float t2 = m2 ? iour : 0.f;
        unsigned long long k0 = ((unsigned long long)(unsigned)__float_as_int(t0) << 32) | lo;
        unsigned long long k1 = ((unsigned long long)(unsigned)__float_as_int(t1) << 32) | lo;
        unsigned long long k2 = ((unsigned long long)(unsigned)__float_as_int(t2) << 32) | lo;
        if (k0 > best0) best0 = k0;
        if (k1 > best1) best1 = k1;
        if (k2 > best2) best2 = k2;
    }
#pragma unroll
    for (int off = 1; off < 8; off <<= 1) {
        unsigned long long o;
        o = __shfl_xor(best0, off, 64); if (o > best0) best0 = o;
        o = __shfl_xor(best1, off, 64); if (o > best1) best1 = o;
        o = __shfl_xor(best2, off, 64); if (o > best2) best2 = o;
    }
    if (jl == 0) {
        size_t kb = ((size_t)b * PCNT + ie) * 3;
        if ((unsigned)(best0 >> 32) >= 0x3F000000u) atomicMax(&keys[kb + 0], best0);
        if ((unsigned)(best1 >> 32) >= 0x3F000000u) atomicMax(&keys[kb + 1], best1);
        if ((unsigned)(best2 >> 32) >= 0x3F000000u) atomicMax(&keys[kb + 2], best2);
    }
}

__global__ __launch_bounds__(256) void k_finalize_loss(
    const unsigned long long* __restrict__ keys, const float* __restrict__ ps,
    const float* __restrict__ labels, const float* __restrict__ logit,
    float* __restrict__ partials, unsigned* __restrict__ doneCnt,
    float* __restrict__ out_loss, int rows, float invB)
{
    int tid = threadIdx.x;
    int row = blockIdx.x * 256 + tid;
    float vals[8] = {0.f, 0.f, 0.f, 0.f, 0.f, 0.f, 0.f, 0.f};
    if (row < rows) {
        int b = row >> 11;
        float I = -1.f; int cls = 3; float wv = 1.f;
#pragma unroll
        for (int c = 0; c < 3; ++c) {
            unsigned long long key = keys[(size_t)row * 3 + c];
            float lab = labels[b * 4 + c];
            if (key != 0ull && lab > 0.f) {
                float t = __uint_as_float((unsigned)(key >> 32));
                if (t >= 0.5f && t > I) {
                    int j = 0x7FFFFFFF - (int)(key & 0xFFFFFFFFull);
                    I = t; cls = c;
                    wv = ps[((size_t)b * PCNT + j) * 4 + c];
                }
            }
        }
        float4 lg = ((const float4*)logit)[row];
        float l = (cls == 0) ? lg.x : (cls == 1) ? lg.y : (cls == 2) ? lg.z : lg.w;
        float p = fminf(fmaxf(l, 1e-7f), 1.f - 1e-7f);
        float om = 1.f - p;
        float fl = -logf(p) * om * om;
        float lab = (cls == 3) ? 1.f : labels[b * 4 + cls];
        float wu = 10.f * expf(l) * (1.f - lab) + lab;
        float contrib = wv * fl * wu;
        vals[cls]     = contrib;
        vals[cls + 4] = 1.f;
    }
#pragma unroll
    for (int comp = 0; comp < 8; ++comp) {
#pragma unroll
        for (int off = 1; off < 64; off <<= 1)
            vals[comp] += __shfl_xor(vals[comp], off, 64);
    }
    __shared__ float wred[4][8];
    __shared__ bool lastBlk;
    int lane = tid & 63, wave = tid >> 6;
    if (lane == 0) {
#pragma unroll
        for (int comp = 0; comp < 8; ++comp) wred[wave][comp] = vals[comp];
    }
    __syncthreads();
    if (tid < 8) {
        partials[blockIdx.x * 8 + tid] =
            wred[0][tid] + wred[1][tid] + wred[2][tid] + wred[3][tid];
        __threadfence();
    }
    __syncthreads();
    if (tid == 0) {
        unsigned old = atomicAdd(doneCnt, 1u);
        lastBlk = (old == gridDim.x - 1);
    }
    __syncthreads();
    if (lastBlk) {
        __threadfence();
        __shared__ float red8[8][32];
        int c = tid & 7, i = tid >> 3;
        float s = 0.f;
        for (int kb = i; kb < (int)gridDim.x; kb += 32) s += partials[kb * 8 + c];
        red8[c][i] = s;
        __syncthreads();
        for (int st = 16; st > 0; st >>= 1) {
            if (i < st) red8[c][i] += red8[c][i + st];
            __syncthreads();
        }
        if (tid == 0) {
            float loss = 0.f;
#pragma unroll
            for (int cc = 0; cc < 4; ++cc)
                loss += red8[cc][0] / (red8[cc + 4][0] + 1e-7f);
            *out_loss = loss * invB;
        }
    }
}

extern "C" void kernel_launch(void* const* d_in, const int* in_sizes, int n_in,
                              void* d_out, int out_size, void* d_ws, size_t ws_size,
                              hipStream_t stream)
{
    const float* inputs = (const float*)d_in[0];
    const float* ps     = (const float*)d_in[1];
    const float* labels = (const float*)d_in[2];
    const float* rois   = (const float*)d_in[3];
    const float* fcw    = (const float*)d_in[4];
    const float* fcb    = (const float*)d_in[5];

    int B = in_sizes[2] / 4;            // 16
    int rows = B * PCNT;                // 32768
    float* out = (float*)d_out;

    char* ws = (char*)d_ws;
    size_t off = 0;
    unsigned long long* keys = (unsigned long long*)(ws + off);
    int nkeys = rows * 3;
    off += (size_t)nkeys * 8;
    off = (off + 255) & ~(size_t)255;
    float* partials = (float*)(ws + off);               off += (size_t)(rows / 256) * 8 * 4;
    unsigned* doneCnt = (unsigned*)(ws + off);          off += 64;
    unsigned* batchDone = (unsigned*)(ws + off);        off += (size_t)B * 64;   // 1 counter / 64B
    int* seedsCnt  = (int*)(ws + off);                  off += (size_t)B * 3 * 4;
    int* seedsAmax = (int*)(ws + off);                  off += (size_t)B * 3 * 4;
    off = (off + 255) & ~(size_t)255;
    int* cellCnt   = (int*)(ws + off);                  off += (size_t)B * 64 * 4;
    off = (off + 255) & ~(size_t)255;
    float4* roisE = (float4*)(ws + off);                off += (size_t)B * CAP_B * 16;
    unsigned* metaU = (unsigned*)(ws + off);            off += (size_t)B * CAP_B * 4;
    bool binned = (ws_size >= off);

    int gemvBlocks = rows / 16;   // 2048
    if (binned) {
        int sb = 8 * B;   // 128 scatter blocks
        k_front<<<sb + gemvBlocks, 256, 0, stream>>>(
            inputs, fcw, fcb, out, ps, rois, keys, nkeys,
            cellCnt, roisE, metaU, doneCnt, batchDone, sb, B);
        k_assign_fin<<<B * 64 + B * 8, 256, 0, stream>>>(
            cellCnt, roisE, metaU, keys, ps, labels, out,
            partials, doneCnt, batchDone, out + (size_t)rows * 4,
            B, 1.f / (float)B);
    } else {
        k_front<<<gemvBlocks, 256, 0, stream>>>(
            inputs, fcw, fcb, out, ps, rois, keys, nkeys,
            cellCnt, roisE, metaU, doneCnt, batchDone, 0, B);
        k_seeds<<<B * 3, 256, 0, stream>>>(ps, seedsCnt, seedsAmax);
        k_assign_fallback<<<B * 64, 256, 0, stream>>>(rois, ps, seedsCnt, seedsAmax, keys);
        k_finalize_loss<<<rows / 256, 256, 0, stream>>>(keys, ps, labels, out, partials,
                                                        doneCnt, out + (size_t)rows * 4,
                                                        rows, 1.f / (float)B);
    }
}

// Round 14
// 88.548 us; speedup vs baseline: 1.4703x; 1.4703x over previous
//
#include <hip/hip_runtime.h>
#include <math.h>

#define PCNT 2048
#define CDIM 512
#define CAP_B (PCNT * 9)        // worst-case entries/batch (box spans <=3x3 cells)

// ------------------------------------------------------------------
// K1 "front": blocks [0, 8B) = prep+scatter per (b, octant);
//             blocks [8B, 8B+rows/16) = gemv+softmax.
// (R12-proven) Block-private scatter: each block recomputes seeds and
// per-(cell,octant) counts, derives disjoint slot ranges, scatters its
// own 256 boxes. Also zeroes keys/doneCnt/batchDone.
// ------------------------------------------------------------------
__global__ __launch_bounds__(256) void k_front(
    const float* __restrict__ in, const float* __restrict__ W,
    const float* __restrict__ bias, float* __restrict__ out,
    const float* __restrict__ ps, const float* __restrict__ rois,
    unsigned long long* __restrict__ keys, int nkeys,
    int* __restrict__ cellCnt, float4* __restrict__ roisE,
    unsigned* __restrict__ metaU, unsigned* __restrict__ doneCnt,
    unsigned* __restrict__ batchDone,
    int scatterBlocks, int B)
{
    __shared__ float4 w_lds[512];
    __shared__ float  sval[256];
    __shared__ int    sidx[256];
    __shared__ int    scnt[256];
    __shared__ int    cnt512[512];     // [cell][octant]
    __shared__ int    cur64[64];
    __shared__ int    amaxS[3], cntS[3];
    int tid = threadIdx.x;
    int bid = blockIdx.x;

    if (bid < scatterBlocks) {
        int b = bid >> 3, oct = bid & 7;
        int share = nkeys / scatterBlocks;
        for (int t = tid; t < share; t += 256) keys[bid * share + t] = 0ull;
        if (bid == 0) {
            if (tid == 0) *doneCnt = 0u;
            if (tid < B) batchDone[tid * 16] = 0u;
        }

        const float4* psb = (const float4*)ps + (size_t)b * PCNT;
        const float4* rb  = (const float4*)rois + (size_t)b * PCNT;

        // ---- seeds: 3 classes, one ps scan ----
        float bv0 = -1e30f, bv1 = -1e30f, bv2 = -1e30f;
        int bi0 = 0, bi1 = 0, bi2 = 0, c0 = 0, c1 = 0, c2 = 0;
#pragma unroll
        for (int t = 0; t < PCNT / 256; ++t) {
            int j = tid + t * 256;
            float4 pv = psb[j];
            if (pv.x > 0.5f) c0++;
            if (pv.x > bv0) { bv0 = pv.x; bi0 = j; }
            if (pv.y > 0.5f) c1++;
            if (pv.y > bv1) { bv1 = pv.y; bi1 = j; }
            if (pv.z > 0.5f) c2++;
            if (pv.z > bv2) { bv2 = pv.z; bi2 = j; }
        }
#pragma unroll
        for (int c = 0; c < 3; ++c) {
            sval[tid] = (c == 0) ? bv0 : (c == 1) ? bv1 : bv2;
            sidx[tid] = (c == 0) ? bi0 : (c == 1) ? bi1 : bi2;
            scnt[tid] = (c == 0) ? c0  : (c == 1) ? c1  : c2;
            __syncthreads();
            for (int s = 128; s > 0; s >>= 1) {
                if (tid < s) {
                    float v2 = sval[tid + s]; int i2 = sidx[tid + s];
                    if (v2 > sval[tid] || (v2 == sval[tid] && i2 < sidx[tid])) { sval[tid] = v2; sidx[tid] = i2; }
                    scnt[tid] += scnt[tid + s];
                }
                __syncthreads();
            }
            if (tid == 0) { amaxS[c] = sidx[0]; cntS[c] = scnt[0]; }
            __syncthreads();
        }

        // ---- counts per (cell, octant) ----
        cnt512[tid] = 0; cnt512[tid + 256] = 0;
        __syncthreads();
#pragma unroll
        for (int t = 0; t < PCNT / 256; ++t) {
            int j = tid + t * 256;
            float4 q = rb[j];
            int jo = j >> 8;
            int cx0 = min(((int)q.x) >> 7, 7), cx1 = min(((int)q.z) >> 7, 7);
            int cy0 = min(((int)q.y) >> 7, 7), cy1 = min(((int)q.w) >> 7, 7);
            for (int cy = cy0; cy <= cy1; ++cy)
                for (int cx = cx0; cx <= cx1; ++cx)
                    atomicAdd(&cnt512[(cy * 8 + cx) * 8 + jo], 1);
        }
        __syncthreads();
        if (tid < 64) {
            int tot = 0, pre = 0;
#pragma unroll
            for (int o = 0; o < 8; ++o) {
                int v = cnt512[tid * 8 + o];
                if (o < oct) pre += v;
                tot += v;
            }
            int incl = tot;
#pragma unroll
            for (int d = 1; d < 64; d <<= 1) {
                int v = __shfl_up(incl, d, 64);
                if (tid >= d) incl += v;
            }
            cur64[tid] = (incl - tot) + pre;
            cellCnt[b * 64 + tid] = tot;
        }
        __syncthreads();
        {
            int j = oct * 256 + tid;
            float4 q  = rb[j];
            float4 pv = psb[j];
            unsigned m0 = ((cntS[0] <= 1) ? (j == amaxS[0]) : (pv.x > 0.5f)) ? 0x10000u : 0u;
            unsigned m1 = ((cntS[1] <= 1) ? (j == amaxS[1]) : (pv.y > 0.5f)) ? 0x20000u : 0u;
            unsigned m2 = ((cntS[2] <= 1) ? (j == amaxS[2]) : (pv.z > 0.5f)) ? 0x40000u : 0u;
            unsigned meta = (unsigned)j | m0 | m1 | m2;
            int cx0 = min(((int)q.x) >> 7, 7), cx1 = min(((int)q.z) >> 7, 7);
            int cy0 = min(((int)q.y) >> 7, 7), cy1 = min(((int)q.w) >> 7, 7);
            for (int cy = cy0; cy <= cy1; ++cy)
                for (int cx = cx0; cx <= cx1; ++cx) {
                    int e = atomicAdd(&cur64[cy * 8 + cx], 1);
                    size_t pos = (size_t)b * CAP_B + e;
                    roisE[pos] = q;
                    metaU[pos] = meta;
                }
        }
    } else {
        // ============ gemv + softmax ============
        int gbid = bid - scatterBlocks;
        if (scatterBlocks == 0) {
            int gid = gbid * 256 + tid;
            if (gid < nkeys) keys[gid] = 0ull;
            if (gid == 0) *doneCnt = 0u;
        }
        const float4* W4 = (const float4*)W;   // [c*128 + q], q = m*16+k
        for (int e = tid; e < 512; e += 256) {
            int k = e & 15, c = (e >> 4) & 3, m = e >> 6;
            w_lds[e] = W4[c * 128 + m * 16 + k];
        }
        __syncthreads();
        int row = gbid * 16 + (tid >> 4);
        int k   = tid & 15;
        const float4* ip = (const float4*)(in + (size_t)row * CDIM);
        float4 v[8];
#pragma unroll
        for (int m = 0; m < 8; ++m) v[m] = ip[m * 16 + k];
        float a0 = 0.f, a1 = 0.f, a2 = 0.f, a3 = 0.f;
#pragma unroll
        for (int m = 0; m < 8; ++m) {
            float4 w0 = w_lds[(m * 4 + 0) * 16 + k];
            float4 w1 = w_lds[(m * 4 + 1) * 16 + k];
            float4 w2 = w_lds[(m * 4 + 2) * 16 + k];
            float4 w3 = w_lds[(m * 4 + 3) * 16 + k];
            a0 += v[m].x*w0.x + v[m].y*w0.y + v[m].z*w0.z + v[m].w*w0.w;
            a1 += v[m].x*w1.x + v[m].y*w1.y + v[m].z*w1.z + v[m].w*w1.w;
            a2 += v[m].x*w2.x + v[m].y*w2.y + v[m].z*w2.z + v[m].w*w2.w;
            a3 += v[m].x*w3.x + v[m].y*w3.y + v[m].z*w3.z + v[m].w*w3.w;
        }
#pragma unroll
        for (int off = 1; off < 16; off <<= 1) {
            a0 += __shfl_xor(a0, off, 64);
            a1 += __shfl_xor(a1, off, 64);
            a2 += __shfl_xor(a2, off, 64);
            a3 += __shfl_xor(a3, off, 64);
        }
        if (k == 0) {
            a0 += bias[0]; a1 += bias[1]; a2 += bias[2]; a3 += bias[3];
            float m = fmaxf(fmaxf(a0, a1), fmaxf(a2, a3));
            float e0 = expf(a0 - m), e1 = expf(a1 - m), e2 = expf(a2 - m), e3 = expf(a3 - m);
            float inv = 1.f / (e0 + e1 + e2 + e3);
            ((float4*)out)[row] = make_float4(e0 * inv, e1 * inv, e2 * inv, e3 * inv);
        }
    }
}

// ------------------------------------------------------------------
// K2: assignment + NON-WAITING fused finalize. Grid = B*64 x 256.
// After assign, each block atomicAdds batchDone[b]; the block seeing
// old==63 (last arriver, no spin) finalizes batch b's 2048 rows
// (8 rows/thread), writes 8 per-batch partials; the globally-last
// batch (doneCnt) reduces the B*8 partials to the loss. Deterministic:
// one block per batch, fixed summation order.
// ------------------------------------------------------------------
__global__ __launch_bounds__(256) void k_assign_fin2(
    const int* __restrict__ cellCnt,
    const float4* __restrict__ roisE, const unsigned* __restrict__ metaU,
    unsigned long long* __restrict__ keys,
    const float* __restrict__ ps, const float* __restrict__ labels,
    const float* __restrict__ logit,
    float* __restrict__ partials, unsigned* __restrict__ doneCnt,
    unsigned* __restrict__ batchDone, float* __restrict__ out_loss,
    int B, float invB)
{
    int tid = threadIdx.x;
    int bid = blockIdx.x;
    int lane = tid & 63;
    int b = bid >> 6;

    // ================= assignment =================
    {
        int cnt = cellCnt[b * 64 + lane];
        int einc = cnt;
#pragma unroll
        for (int d = 1; d < 64; d <<= 1) {
            int v = __shfl_up(einc, d, 64);
            if (lane >= d) einc += v;
        }
        int eexc = einc - cnt;
        int grp = (cnt + 7) >> 3;
        int ginc = grp;
#pragma unroll
        for (int d = 1; d < 64; d <<= 1) {
            int v = __shfl_up(ginc, d, 64);
            if (lane >= d) ginc += v;
        }
        int gexc = ginc - grp;
        int total = __shfl(ginc, 63, 64);
        int widx = ((bid & 63) << 2) + (tid >> 6);
        int il = lane >> 3, jl = lane & 7;

        for (int idx = widx; idx < total; idx += 256) {
            unsigned long long msk = __ballot(idx >= gexc && idx < ginc);
            int cell = __ffsll((unsigned long long)msk) - 1;
            int g = idx - __shfl(gexc, cell, 64);
            int n = __shfl(cnt, cell, 64);
            size_t base = (size_t)b * CAP_B + __shfl(eexc, cell, 64);
            int ie = g * 8 + il;
            bool ivalid = ie < n;
            int iload = ivalid ? ie : 0;
            float4 r = roisE[base + iload];
            int i_prop = (int)(metaU[base + iload] & 0xFFFFu);
            float areaA = (r.z - r.x) * (r.w - r.y);

            unsigned long long best0 = 0, best1 = 0, best2 = 0;
            for (int e = jl; e < n; e += 8) {
                float4 q = roisE[base + e];
                unsigned mu = metaU[base + e];
                float lx = fmaxf(r.x, q.x), ly = fmaxf(r.y, q.y);
                float rx = fminf(r.z, q.z), ry = fminf(r.w, q.w);
                float ww = fmaxf(rx - lx, 0.f);
                float hh = fmaxf(ry - ly, 0.f);
                float inter = ww * hh;
                float areaB = (q.z - q.x) * (q.w - q.y);
                float u = (areaA + areaB) - inter;
                float ioup1 = fmaf(inter, __builtin_amdgcn_rcpf(u), 1.0f);
                float iour = ioup1 - 1.0f;
                unsigned lo = 0x7FFFFFFFu - (mu & 0xFFFFu);
                float t0 = (mu & 0x10000u) ? iour : 0.f;
                float t1 = (mu & 0x20000u) ? iour : 0.f;
                float t2 = (mu & 0x40000u) ? iour : 0.f;
                unsigned long long k0 = ((unsigned long long)(unsigned)__float_as_int(t0) << 32) | lo;
                unsigned long long k1 = ((unsigned long long)(unsigned)__float_as_int(t1) << 32) | lo;
                unsigned long long k2 = ((unsigned long long)(unsigned)__float_as_int(t2) << 32) | lo;
                if (k0 > best0) best0 = k0;
                if (k1 > best1) best1 = k1;
                if (k2 > best2) best2 = k2;
            }
#pragma unroll
            for (int off = 1; off < 8; off <<= 1) {
                unsigned long long o;
                o = __shfl_xor(best0, off, 64); if (o > best0) best0 = o;
                o = __shfl_xor(best1, off, 64); if (o > best1) best1 = o;
                o = __shfl_xor(best2, off, 64); if (o > best2) best2 = o;
            }
            if (jl == 0 && ivalid) {
                size_t kb = ((size_t)b * PCNT + i_prop) * 3;
                if ((unsigned)(best0 >> 32) >= 0x3F000000u) atomicMax(&keys[kb + 0], best0);
                if ((unsigned)(best1 >> 32) >= 0x3F000000u) atomicMax(&keys[kb + 1], best1);
                if ((unsigned)(best2 >> 32) >= 0x3F000000u) atomicMax(&keys[kb + 2], best2);
            }
        }
    }

    // ============ last-arriver finalize (no waiting) ============
    __shared__ bool lastOfBatch;
    __syncthreads();
    if (tid == 0) {
        __threadfence();
        unsigned old = atomicAdd(&batchDone[b * 16], 1u);
        lastOfBatch = (old == 63u);
    }
    __syncthreads();
    if (!lastOfBatch) return;
    __threadfence();   // acquire: see all of batch b's keys

    float v0 = 0.f, v1 = 0.f, v2 = 0.f, v3 = 0.f;
    float n0 = 0.f, n1 = 0.f, n2 = 0.f, n3 = 0.f;
    float lab0 = labels[b * 4 + 0];
    float lab1 = labels[b * 4 + 1];
    float lab2 = labels[b * 4 + 2];
#pragma unroll
    for (int t = 0; t < PCNT / 256; ++t) {
        int r = t * 256 + tid;
        int row = b * PCNT + r;
        float I = -1.f; int cls = 3; float wv = 1.f;
#pragma unroll
        for (int c = 0; c < 3; ++c) {
            unsigned long long key = keys[(size_t)row * 3 + c];
            float lab = (c == 0) ? lab0 : (c == 1) ? lab1 : lab2;
            if (key != 0ull && lab > 0.f) {
                float tt = __uint_as_float((unsigned)(key >> 32));
                if (tt >= 0.5f && tt > I) {
                    int j = 0x7FFFFFFF - (int)(key & 0xFFFFFFFFull);
                    I = tt; cls = c;
                    wv = ps[((size_t)b * PCNT + j) * 4 + c];
                }
            }
        }
        float4 lg = ((const float4*)logit)[row];
        float l = (cls == 0) ? lg.x : (cls == 1) ? lg.y : (cls == 2) ? lg.z : lg.w;
        float p = fminf(fmaxf(l, 1e-7f), 1.f - 1e-7f);
        float om = 1.f - p;
        float fl = -logf(p) * om * om;
        float lab = (cls == 0) ? lab0 : (cls == 1) ? lab1 : (cls == 2) ? lab2 : 1.f;
        float wu = 10.f * expf(l) * (1.f - lab) + lab;
        float contrib = wv * fl * wu;
        v0 += (cls == 0) ? contrib : 0.f;  n0 += (cls == 0) ? 1.f : 0.f;
        v1 += (cls == 1) ? contrib : 0.f;  n1 += (cls == 1) ? 1.f : 0.f;
        v2 += (cls == 2) ? contrib : 0.f;  n2 += (cls == 2) ? 1.f : 0.f;
        v3 += (cls == 3) ? contrib : 0.f;  n3 += (cls == 3) ? 1.f : 0.f;
    }
    float vals[8] = {v0, v1, v2, v3, n0, n1, n2, n3};
#pragma unroll
    for (int comp = 0; comp < 8; ++comp) {
#pragma unroll
        for (int off = 1; off < 64; off <<= 1)
            vals[comp] += __shfl_xor(vals[comp], off, 64);
    }
    __shared__ float wred[4][8];
    __shared__ bool lastBatch;
    int wave = tid >> 6;
    if (lane == 0) {
#pragma unroll
        for (int comp = 0; comp < 8; ++comp) wred[wave][comp] = vals[comp];
    }
    __syncthreads();
    if (tid < 8) {
        partials[b * 8 + tid] =
            wred[0][tid] + wred[1][tid] + wred[2][tid] + wred[3][tid];
        __threadfence();
    }
    __syncthreads();
    if (tid == 0) {
        unsigned old = atomicAdd(doneCnt, 1u);
        lastBatch = (old == (unsigned)(B - 1));
    }
    __syncthreads();
    if (lastBatch) {
        __threadfence();
        __shared__ float red8[8][32];
        int c = tid & 7, i = tid >> 3;   // i in [0,32)
        float s = 0.f;
        for (int kb = i; kb < B; kb += 32) s += partials[kb * 8 + c];
        red8[c][i] = s;
        __syncthreads();
        for (int st = 16; st > 0; st >>= 1) {
            if (i < st) red8[c][i] += red8[c][i + st];
            __syncthreads();
        }
        if (tid == 0) {
            float loss = 0.f;
#pragma unroll
            for (int cc = 0; cc < 4; ++cc)
                loss += red8[cc][0] / (red8[cc + 4][0] + 1e-7f);
            *out_loss = loss * invB;
        }
    }
}

// ------------------------------------------------------------------
// Fallback path (ws too small): seeds + full-scan assign + finalize.
// ------------------------------------------------------------------
__global__ __launch_bounds__(256) void k_seeds(
    const float* __restrict__ ps, int* __restrict__ seedsCnt,
    int* __restrict__ seedsAmax)
{
    int b = blockIdx.x / 3, c = blockIdx.x % 3;
    int tid = threadIdx.x;
    __shared__ float sval[256];
    __shared__ int   sidx[256];
    __shared__ int   scnt[256];
    float bestv = -1e30f; int besti = 0; int cnt = 0;
#pragma unroll
    for (int t = 0; t < PCNT / 256; ++t) {
        int j = tid + t * 256;
        float v = ps[((size_t)b * PCNT + j) * 4 + c];
        if (v > 0.5f) cnt++;
        if (v > bestv) { bestv = v; besti = j; }
    }
    sval[tid] = bestv; sidx[tid] = besti; scnt[tid] = cnt;
    __syncthreads();
    for (int s = 128; s > 0; s >>= 1) {
        if (tid < s) {
            float v2 = sval[tid + s]; int i2 = sidx[tid + s];
            if (v2 > sval[tid] || (v2 == sval[tid] && i2 < sidx[tid])) { sval[tid] = v2; sidx[tid] = i2; }
            scnt[tid] += scnt[tid + s];
        }
        __syncthreads();
    }
    if (tid == 0) { seedsCnt[blockIdx.x] = scnt[0]; seedsAmax[blockIdx.x] = sidx[0]; }
}

__global__ __launch_bounds__(256) void k_assign_fallback(
    const float* __restrict__ rois, const float* __restrict__ ps,
    const int* __restrict__ seedsCnt, const int* __restrict__ seedsAmax,
    unsigned long long* __restrict__ keys)
{
    int tid = threadIdx.x;
    int item = blockIdx.x * 4 + (tid >> 6);
    int b = item >> 8;
    int g = item & 255;
    int lane = tid & 63, il = lane >> 3, jl = lane & 7;
    int ie = g * 8 + il;
    const float4* rb = (const float4*)rois + (size_t)b * PCNT;
    const float4* pb = (const float4*)ps + (size_t)b * PCNT;
    float4 r = rb[ie];
    float areaA = (r.z - r.x) * (r.w - r.y);
    int c0 = seedsCnt[b*3+0], a0 = seedsAmax[b*3+0];
    int c1 = seedsCnt[b*3+1], a1 = seedsAmax[b*3+1];
    int c2 = seedsCnt[b*3+2], a2 = seedsAmax[b*3+2];

    unsigned long long best0 = 0, best1 = 0, best2 = 0;
    for (int e = jl; e < PCNT; e += 8) {
        float4 q = rb[e];
        float4 pv = pb[e];
        bool m0 = (c0 <= 1) ? (e == a0) : (pv.x > 0.5f);
        bool m1 = (c1 <= 1) ? (e == a1) : (pv.y > 0.5f);
        bool m2 = (c2 <= 1) ? (e == a2) : (pv.z > 0.5f);
        float lx = fmaxf(r.x, q.x), ly = fmaxf(r.y, q.y);
        float rx = fminf(r.z, q.z), ry = fminf(r.w, q.w);
        float ww = fmaxf(rx - lx, 0.f);
        float hh = fmaxf(ry - ly, 0.f);
        float inter = ww * hh;
        float areaB = (q.z - q.x) * (q.w - q.y);
        float u = (areaA + areaB) - inter;
        float ioup1 = fmaf(inter, __builtin_amdgcn_rcpf(u), 1.0f);
        float iour = ioup1 - 1.0f;
        unsigned lo = 0x7FFFFFFFu - (unsigned)e;
        float t0 = m0 ? iour : 0.f;
        float t1 = m1 ? iour : 0.f;
        float t2 = m2 ? iour : 0.f;
        unsigned long long k0 = ((unsigned long long)(unsigned)__float_as_int(t0) << 32) | lo;
        unsigned long long k1 = ((unsigned long long)(unsigned)__float_as_int(t1) << 32) | lo;
        unsigned long long k2 = ((unsigned long long)(unsigned)__float_as_int(t2) << 32) | lo;
        if (k0 > best0) best0 = k0;
        if (k1 > best1) best1 = k1;
        if (k2 > best2) best2 = k2;
    }
#pragma unroll
    for (int off = 1; off < 8; off <<= 1) {
        unsigned long long o;
        o = __shfl_xor(best0, off, 64); if (o > best0) best0 = o;
        o = __shfl_xor(best1, off, 64); if (o > best1) best1 = o;
        o = __shfl_xor(best2, off, 64); if (o > best2) best2 = o;
    }
    if (jl == 0) {
        size_t kb = ((size_t)b * PCNT + ie) * 3;
        if ((unsigned)(best0 >> 32) >= 0x3F000000u) atomicMax(&keys[kb + 0], best0);
        if ((unsigned)(best1 >> 32) >= 0x3F000000u) atomicMax(&keys[kb + 1], best1);
        if ((unsigned)(best2 >> 32) >= 0x3F000000u) atomicMax(&keys[kb + 2], best2);
    }
}

__global__ __launch_bounds__(256) void k_finalize_loss(
    const unsigned long long* __restrict__ keys, const float* __restrict__ ps,
    const float* __restrict__ labels, const float* __restrict__ logit,
    float* __restrict__ partials, unsigned* __restrict__ doneCnt,
    float* __restrict__ out_loss, int rows, float invB)
{
    int tid = threadIdx.x;
    int row = blockIdx.x * 256 + tid;
    float vals[8] = {0.f, 0.f, 0.f, 0.f, 0.f, 0.f, 0.f, 0.f};
    if (row < rows) {
        int b = row >> 11;
        float I = -1.f; int cls = 3; float wv = 1.f;
#pragma unroll
        for (int c = 0; c < 3; ++c) {
            unsigned long long key = keys[(size_t)row * 3 + c];
            float lab = labels[b * 4 + c];
            if (key != 0ull && lab > 0.f) {
                float t = __uint_as_float((unsigned)(key >> 32));
                if (t >= 0.5f && t > I) {
                    int j = 0x7FFFFFFF - (int)(key & 0xFFFFFFFFull);
                    I = t; cls = c;
                    wv = ps[((size_t)b * PCNT + j) * 4 + c];
                }
            }
        }
        float4 lg = ((const float4*)logit)[row];
        float l = (cls == 0) ? lg.x : (cls == 1) ? lg.y : (cls == 2) ? lg.z : lg.w;
        float p = fminf(fmaxf(l, 1e-7f), 1.f - 1e-7f);
        float om = 1.f - p;
        float fl = -logf(p) * om * om;
        float lab = (cls == 3) ? 1.f : labels[b * 4 + cls];
        float wu = 10.f * expf(l) * (1.f - lab) + lab;
        float contrib = wv * fl * wu;
        vals[0] = (cls == 0) ? contrib : 0.f; vals[4] = (cls == 0) ? 1.f : 0.f;
        vals[1] = (cls == 1) ? contrib : 0.f; vals[5] = (cls == 1) ? 1.f : 0.f;
        vals[2] = (cls == 2) ? contrib : 0.f; vals[6] = (cls == 2) ? 1.f : 0.f;
        vals[3] = (cls == 3) ? contrib : 0.f; vals[7] = (cls == 3) ? 1.f : 0.f;
    }
#pragma unroll
    for (int comp = 0; comp < 8; ++comp) {
#pragma unroll
        for (int off = 1; off < 64; off <<= 1)
            vals[comp] += __shfl_xor(vals[comp], off, 64);
    }
    __shared__ float wred[4][8];
    __shared__ bool lastBlk;
    int lane = tid & 63, wave = tid >> 6;
    if (lane == 0) {
#pragma unroll
        for (int comp = 0; comp < 8; ++comp) wred[wave][comp] = vals[comp];
    }
    __syncthreads();
    if (tid < 8) {
        partials[blockIdx.x * 8 + tid] =
            wred[0][tid] + wred[1][tid] + wred[2][tid] + wred[3][tid];
        __threadfence();
    }
    __syncthreads();
    if (tid == 0) {
        unsigned old = atomicAdd(doneCnt, 1u);
        lastBlk = (old == gridDim.x - 1);
    }
    __syncthreads();
    if (lastBlk) {
        __threadfence();
        __shared__ float red8[8][32];
        int c = tid & 7, i = tid >> 3;
        float s = 0.f;
        for (int kb = i; kb < (int)gridDim.x; kb += 32) s += partials[kb * 8 + c];
        red8[c][i] = s;
        __syncthreads();
        for (int st = 16; st > 0; st >>= 1) {
            if (i < st) red8[c][i] += red8[c][i + st];
            __syncthreads();
        }
        if (tid == 0) {
            float loss = 0.f;
#pragma unroll
            for (int cc = 0; cc < 4; ++cc)
                loss += red8[cc][0] / (red8[cc + 4][0] + 1e-7f);
            *out_loss = loss * invB;
        }
    }
}

extern "C" void kernel_launch(void* const* d_in, const int* in_sizes, int n_in,
                              void* d_out, int out_size, void* d_ws, size_t ws_size,
                              hipStream_t stream)
{
    const float* inputs = (const float*)d_in[0];
    const float* ps     = (const float*)d_in[1];
    const float* labels = (const float*)d_in[2];
    const float* rois   = (const float*)d_in[3];
    const float* fcw    = (const float*)d_in[4];
    const float* fcb    = (const float*)d_in[5];

    int B = in_sizes[2] / 4;            // 16
    int rows = B * PCNT;                // 32768
    float* out = (float*)d_out;

    char* ws = (char*)d_ws;
    size_t off = 0;
    unsigned long long* keys = (unsigned long long*)(ws + off);
    int nkeys = rows * 3;
    off += (size_t)nkeys * 8;
    off = (off + 255) & ~(size_t)255;
    float* partials = (float*)(ws + off);               off += (size_t)(rows / 256) * 8 * 4;
    unsigned* doneCnt = (unsigned*)(ws + off);          off += 64;
    unsigned* batchDone = (unsigned*)(ws + off);        off += (size_t)B * 64;   // 1 counter / 64B
    int* seedsCnt  = (int*)(ws + off);                  off += (size_t)B * 3 * 4;
    int* seedsAmax = (int*)(ws + off);                  off += (size_t)B * 3 * 4;
    off = (off + 255) & ~(size_t)255;
    int* cellCnt   = (int*)(ws + off);                  off += (size_t)B * 64 * 4;
    off = (off + 255) & ~(size_t)255;
    float4* roisE = (float4*)(ws + off);                off += (size_t)B * CAP_B * 16;
    unsigned* metaU = (unsigned*)(ws + off);            off += (size_t)B * CAP_B * 4;
    bool binned = (ws_size >= off) && (B <= 16384);

    int gemvBlocks = rows / 16;   // 2048
    if (binned) {
        int sb = 8 * B;   // 128 scatter blocks
        k_front<<<sb + gemvBlocks, 256, 0, stream>>>(
            inputs, fcw, fcb, out, ps, rois, keys, nkeys,
            cellCnt, roisE, metaU, doneCnt, batchDone, sb, B);
        k_assign_fin2<<<B * 64, 256, 0, stream>>>(
            cellCnt, roisE, metaU, keys, ps, labels, out,
            partials, doneCnt, batchDone, out + (size_t)rows * 4,
            B, 1.f / (float)B);
    } else {
        k_front<<<gemvBlocks, 256, 0, stream>>>(
            inputs, fcw, fcb, out, ps, rois, keys, nkeys,
            cellCnt, roisE, metaU, doneCnt, batchDone, 0, B);
        k_seeds<<<B * 3, 256, 0, stream>>>(ps, seedsCnt, seedsAmax);
        k_assign_fallback<<<B * 64, 256, 0, stream>>>(rois, ps, seedsCnt, seedsAmax, keys);
        k_finalize_loss<<<rows / 256, 256, 0, stream>>>(keys, ps, labels, out, partials,
                                                        doneCnt, out + (size_t)rows * 4,
                                                        rows, 1.f / (float)B);
    }
}

// Round 15
// 59.750 us; speedup vs baseline: 2.1789x; 1.4820x over previous
//
#include <hip/hip_runtime.h>
#include <math.h>

#define PCNT 2048
#define CDIM 512
#define CAP_B (PCNT * 9)        // worst-case entries/batch (box spans <=3x3 cells)

// ------------------------------------------------------------------
// K1 "front": blocks [0, 8B) = prep+scatter per (b, octant);
//             blocks [8B, 8B+rows/16) = gemv+softmax.
// (R12-proven) Block-private scatter: each block recomputes seeds and
// per-(cell,octant) counts, derives disjoint slot ranges, scatters its
// own 256 boxes. Also zeroes keys/doneCnt.
// ------------------------------------------------------------------
__global__ __launch_bounds__(256) void k_front(
    const float* __restrict__ in, const float* __restrict__ W,
    const float* __restrict__ bias, float* __restrict__ out,
    const float* __restrict__ ps, const float* __restrict__ rois,
    unsigned long long* __restrict__ keys, int nkeys,
    int* __restrict__ cellCnt, float4* __restrict__ roisE,
    unsigned* __restrict__ metaU, unsigned* __restrict__ doneCnt,
    int scatterBlocks, int B)
{
    __shared__ float4 w_lds[512];
    __shared__ float  sval[256];
    __shared__ int    sidx[256];
    __shared__ int    scnt[256];
    __shared__ int    cnt512[512];     // [cell][octant]
    __shared__ int    cur64[64];
    __shared__ int    amaxS[3], cntS[3];
    int tid = threadIdx.x;
    int bid = blockIdx.x;

    if (bid < scatterBlocks) {
        int b = bid >> 3, oct = bid & 7;
        int share = nkeys / scatterBlocks;
        for (int t = tid; t < share; t += 256) keys[bid * share + t] = 0ull;
        if (bid == 0 && tid == 0) *doneCnt = 0u;

        const float4* psb = (const float4*)ps + (size_t)b * PCNT;
        const float4* rb  = (const float4*)rois + (size_t)b * PCNT;

        // ---- seeds: 3 classes, one ps scan ----
        float bv0 = -1e30f, bv1 = -1e30f, bv2 = -1e30f;
        int bi0 = 0, bi1 = 0, bi2 = 0, c0 = 0, c1 = 0, c2 = 0;
#pragma unroll
        for (int t = 0; t < PCNT / 256; ++t) {
            int j = tid + t * 256;
            float4 pv = psb[j];
            if (pv.x > 0.5f) c0++;
            if (pv.x > bv0) { bv0 = pv.x; bi0 = j; }
            if (pv.y > 0.5f) c1++;
            if (pv.y > bv1) { bv1 = pv.y; bi1 = j; }
            if (pv.z > 0.5f) c2++;
            if (pv.z > bv2) { bv2 = pv.z; bi2 = j; }
        }
#pragma unroll
        for (int c = 0; c < 3; ++c) {
            sval[tid] = (c == 0) ? bv0 : (c == 1) ? bv1 : bv2;
            sidx[tid] = (c == 0) ? bi0 : (c == 1) ? bi1 : bi2;
            scnt[tid] = (c == 0) ? c0  : (c == 1) ? c1  : c2;
            __syncthreads();
            for (int s = 128; s > 0; s >>= 1) {
                if (tid < s) {
                    float v2 = sval[tid + s]; int i2 = sidx[tid + s];
                    if (v2 > sval[tid] || (v2 == sval[tid] && i2 < sidx[tid])) { sval[tid] = v2; sidx[tid] = i2; }
                    scnt[tid] += scnt[tid + s];
                }
                __syncthreads();
            }
            if (tid == 0) { amaxS[c] = sidx[0]; cntS[c] = scnt[0]; }
            __syncthreads();
        }

        // ---- counts per (cell, octant) ----
        cnt512[tid] = 0; cnt512[tid + 256] = 0;
        __syncthreads();
#pragma unroll
        for (int t = 0; t < PCNT / 256; ++t) {
            int j = tid + t * 256;
            float4 q = rb[j];
            int jo = j >> 8;
            int cx0 = min(((int)q.x) >> 7, 7), cx1 = min(((int)q.z) >> 7, 7);
            int cy0 = min(((int)q.y) >> 7, 7), cy1 = min(((int)q.w) >> 7, 7);
            for (int cy = cy0; cy <= cy1; ++cy)
                for (int cx = cx0; cx <= cx1; ++cx)
                    atomicAdd(&cnt512[(cy * 8 + cx) * 8 + jo], 1);
        }
        __syncthreads();
        if (tid < 64) {
            int tot = 0, pre = 0;
#pragma unroll
            for (int o = 0; o < 8; ++o) {
                int v = cnt512[tid * 8 + o];
                if (o < oct) pre += v;
                tot += v;
            }
            int incl = tot;
#pragma unroll
            for (int d = 1; d < 64; d <<= 1) {
                int v = __shfl_up(incl, d, 64);
                if (tid >= d) incl += v;
            }
            cur64[tid] = (incl - tot) + pre;
            cellCnt[b * 64 + tid] = tot;
        }
        __syncthreads();
        {
            int j = oct * 256 + tid;
            float4 q  = rb[j];
            float4 pv = psb[j];
            unsigned m0 = ((cntS[0] <= 1) ? (j == amaxS[0]) : (pv.x > 0.5f)) ? 0x10000u : 0u;
            unsigned m1 = ((cntS[1] <= 1) ? (j == amaxS[1]) : (pv.y > 0.5f)) ? 0x20000u : 0u;
            unsigned m2 = ((cntS[2] <= 1) ? (j == amaxS[2]) : (pv.z > 0.5f)) ? 0x40000u : 0u;
            unsigned meta = (unsigned)j | m0 | m1 | m2;
            int cx0 = min(((int)q.x) >> 7, 7), cx1 = min(((int)q.z) >> 7, 7);
            int cy0 = min(((int)q.y) >> 7, 7), cy1 = min(((int)q.w) >> 7, 7);
            for (int cy = cy0; cy <= cy1; ++cy)
                for (int cx = cx0; cx <= cx1; ++cx) {
                    int e = atomicAdd(&cur64[cy * 8 + cx], 1);
                    size_t pos = (size_t)b * CAP_B + e;
                    roisE[pos] = q;
                    metaU[pos] = meta;
                }
        }
    } else {
        // ============ gemv + softmax ============
        int gbid = bid - scatterBlocks;
        if (scatterBlocks == 0) {
            int gid = gbid * 256 + tid;
            if (gid < nkeys) keys[gid] = 0ull;
            if (gid == 0) *doneCnt = 0u;
        }
        const float4* W4 = (const float4*)W;   // [c*128 + q], q = m*16+k
        for (int e = tid; e < 512; e += 256) {
            int k = e & 15, c = (e >> 4) & 3, m = e >> 6;
            w_lds[e] = W4[c * 128 + m * 16 + k];
        }
        __syncthreads();
        int row = gbid * 16 + (tid >> 4);
        int k   = tid & 15;
        const float4* ip = (const float4*)(in + (size_t)row * CDIM);
        float4 v[8];
#pragma unroll
        for (int m = 0; m < 8; ++m) v[m] = ip[m * 16 + k];
        float a0 = 0.f, a1 = 0.f, a2 = 0.f, a3 = 0.f;
#pragma unroll
        for (int m = 0; m < 8; ++m) {
            float4 w0 = w_lds[(m * 4 + 0) * 16 + k];
            float4 w1 = w_lds[(m * 4 + 1) * 16 + k];
            float4 w2 = w_lds[(m * 4 + 2) * 16 + k];
            float4 w3 = w_lds[(m * 4 + 3) * 16 + k];
            a0 += v[m].x*w0.x + v[m].y*w0.y + v[m].z*w0.z + v[m].w*w0.w;
            a1 += v[m].x*w1.x + v[m].y*w1.y + v[m].z*w1.z + v[m].w*w1.w;
            a2 += v[m].x*w2.x + v[m].y*w2.y + v[m].z*w2.z + v[m].w*w2.w;
            a3 += v[m].x*w3.x + v[m].y*w3.y + v[m].z*w3.z + v[m].w*w3.w;
        }
#pragma unroll
        for (int off = 1; off < 16; off <<= 1) {
            a0 += __shfl_xor(a0, off, 64);
            a1 += __shfl_xor(a1, off, 64);
            a2 += __shfl_xor(a2, off, 64);
            a3 += __shfl_xor(a3, off, 64);
        }
        if (k == 0) {
            a0 += bias[0]; a1 += bias[1]; a2 += bias[2]; a3 += bias[3];
            float m = fmaxf(fmaxf(a0, a1), fmaxf(a2, a3));
            float e0 = expf(a0 - m), e1 = expf(a1 - m), e2 = expf(a2 - m), e3 = expf(a3 - m);
            float inv = 1.f / (e0 + e1 + e2 + e3);
            ((float4*)out)[row] = make_float4(e0 * inv, e1 * inv, e2 * inv, e3 * inv);
        }
    }
}

// ------------------------------------------------------------------
// K2: assignment. Grid = B*128 x 256 (8 waves/SIMD for latency
// hiding). Entry loop unrolled x2: both 20B entry loads issued before
// either compute (duplicate-entry trick when e+8>=n: idempotent under
// key-max, no masking needed). u64 key = (iou_bits<<32)|(0x7FFFFFFF-j).
// ------------------------------------------------------------------
__global__ __launch_bounds__(256) void k_assign5(
    const int* __restrict__ cellCnt,
    const float4* __restrict__ roisE, const unsigned* __restrict__ metaU,
    unsigned long long* __restrict__ keys)
{
    int tid = threadIdx.x;
    int b = blockIdx.x >> 7;           // 128 blocks per batch
    int lane = tid & 63;
    int cnt = cellCnt[b * 64 + lane];
    int einc = cnt;
#pragma unroll
    for (int d = 1; d < 64; d <<= 1) {
        int v = __shfl_up(einc, d, 64);
        if (lane >= d) einc += v;
    }
    int eexc = einc - cnt;
    int grp = (cnt + 7) >> 3;
    int ginc = grp;
#pragma unroll
    for (int d = 1; d < 64; d <<= 1) {
        int v = __shfl_up(ginc, d, 64);
        if (lane >= d) ginc += v;
    }
    int gexc = ginc - grp;
    int total = __shfl(ginc, 63, 64);
    int widx = ((blockIdx.x & 127) << 2) + (tid >> 6);
    int il = lane >> 3, jl = lane & 7;

    for (int idx = widx; idx < total; idx += 512) {
        unsigned long long msk = __ballot(idx >= gexc && idx < ginc);
        int cell = __ffsll((unsigned long long)msk) - 1;
        int g = idx - __shfl(gexc, cell, 64);
        int n = __shfl(cnt, cell, 64);
        size_t base = (size_t)b * CAP_B + __shfl(eexc, cell, 64);
        int ie = g * 8 + il;
        bool ivalid = ie < n;
        int iload = ivalid ? ie : 0;
        float4 r = roisE[base + iload];
        int i_prop = (int)(metaU[base + iload] & 0xFFFFu);
        float areaA = (r.z - r.x) * (r.w - r.y);

        unsigned long long best0 = 0, best1 = 0, best2 = 0;
        for (int e = jl; e < n; e += 16) {
            int eB = (e + 8 < n) ? e + 8 : e;    // duplicate of A when OOR
            float4 qA = roisE[base + e];
            unsigned muA = metaU[base + e];
            float4 qB = roisE[base + eB];
            unsigned muB = metaU[base + eB];
            // ---- entry A ----
            {
                float lx = fmaxf(r.x, qA.x), ly = fmaxf(r.y, qA.y);
                float rx = fminf(r.z, qA.z), ry = fminf(r.w, qA.w);
                float ww = fmaxf(rx - lx, 0.f);
                float hh = fmaxf(ry - ly, 0.f);
                float inter = ww * hh;
                float areaB = (qA.z - qA.x) * (qA.w - qA.y);
                float u = (areaA + areaB) - inter;
                float iour = fmaf(inter, __builtin_amdgcn_rcpf(u), 1.0f) - 1.0f;
                unsigned lo = 0x7FFFFFFFu - (muA & 0xFFFFu);
                float t0 = (muA & 0x10000u) ? iour : 0.f;
                float t1 = (muA & 0x20000u) ? iour : 0.f;
                float t2 = (muA & 0x40000u) ? iour : 0.f;
                unsigned long long k0 = ((unsigned long long)(unsigned)__float_as_int(t0) << 32) | lo;
                unsigned long long k1 = ((unsigned long long)(unsigned)__float_as_int(t1) << 32) | lo;
                unsigned long long k2 = ((unsigned long long)(unsigned)__float_as_int(t2) << 32) | lo;
                if (k0 > best0) best0 = k0;
                if (k1 > best1) best1 = k1;
                if (k2 > best2) best2 = k2;
            }
            // ---- entry B ----
            {
                float lx = fmaxf(r.x, qB.x), ly = fmaxf(r.y, qB.y);
                float rx = fminf(r.z, qB.z), ry = fminf(r.w, qB.w);
                float ww = fmaxf(rx - lx, 0.f);
                float hh = fmaxf(ry - ly, 0.f);
                float inter = ww * hh;
                float areaB = (qB.z - qB.x) * (qB.w - qB.y);
                float u = (areaA + areaB) - inter;
                float iour = fmaf(inter, __builtin_amdgcn_rcpf(u), 1.0f) - 1.0f;
                unsigned lo = 0x7FFFFFFFu - (muB & 0xFFFFu);
                float t0 = (muB & 0x10000u) ? iour : 0.f;
                float t1 = (muB & 0x20000u) ? iour : 0.f;
                float t2 = (muB & 0x40000u) ? iour : 0.f;
                unsigned long long k0 = ((unsigned long long)(unsigned)__float_as_int(t0) << 32) | lo;
                unsigned long long k1 = ((unsigned long long)(unsigned)__float_as_int(t1) << 32) | lo;
                unsigned long long k2 = ((unsigned long long)(unsigned)__float_as_int(t2) << 32) | lo;
                if (k0 > best0) best0 = k0;
                if (k1 > best1) best1 = k1;
                if (k2 > best2) best2 = k2;
            }
        }
#pragma unroll
        for (int off = 1; off < 8; off <<= 1) {
            unsigned long long o;
            o = __shfl_xor(best0, off, 64); if (o > best0) best0 = o;
            o = __shfl_xor(best1, off, 64); if (o > best1) best1 = o;
            o = __shfl_xor(best2, off, 64); if (o > best2) best2 = o;
        }
        if (jl == 0 && ivalid) {
            size_t kb = ((size_t)b * PCNT + i_prop) * 3;
            if ((unsigned)(best0 >> 32) >= 0x3F000000u) atomicMax(&keys[kb + 0], best0);
            if ((unsigned)(best1 >> 32) >= 0x3F000000u) atomicMax(&keys[kb + 1], best1);
            if ((unsigned)(best2 >> 32) >= 0x3F000000u) atomicMax(&keys[kb + 2], best2);
        }
    }
}

// ------------------------------------------------------------------
// Fallback helpers (ws too small): standalone seeds + full scan.
// ------------------------------------------------------------------
__global__ __launch_bounds__(256) void k_seeds(
    const float* __restrict__ ps, int* __restrict__ seedsCnt,
    int* __restrict__ seedsAmax)
{
    int b = blockIdx.x / 3, c = blockIdx.x % 3;
    int tid = threadIdx.x;
    __shared__ float sval[256];
    __shared__ int   sidx[256];
    __shared__ int   scnt[256];
    float bestv = -1e30f; int besti = 0; int cnt = 0;
#pragma unroll
    for (int t = 0; t < PCNT / 256; ++t) {
        int j = tid + t * 256;
        float v = ps[((size_t)b * PCNT + j) * 4 + c];
        if (v > 0.5f) cnt++;
        if (v > bestv) { bestv = v; besti = j; }
    }
    sval[tid] = bestv; sidx[tid] = besti; scnt[tid] = cnt;
    __syncthreads();
    for (int s = 128; s > 0; s >>= 1) {
        if (tid < s) {
            float v2 = sval[tid + s]; int i2 = sidx[tid + s];
            if (v2 > sval[tid] || (v2 == sval[tid] && i2 < sidx[tid])) { sval[tid] = v2; sidx[tid] = i2; }
            scnt[tid] += scnt[tid + s];
        }
        __syncthreads();
    }
    if (tid == 0) { seedsCnt[blockIdx.x] = scnt[0]; seedsAmax[blockIdx.x] = sidx[0]; }
}

__global__ __launch_bounds__(256) void k_assign_fallback(
    const float* __restrict__ rois, const float* __restrict__ ps,
    const int* __restrict__ seedsCnt, const int* __restrict__ seedsAmax,
    unsigned long long* __restrict__ keys)
{
    int tid = threadIdx.x;
    int item = blockIdx.x * 4 + (tid >> 6);
    int b = item >> 8;
    int g = item & 255;
    int lane = tid & 63, il = lane >> 3, jl = lane & 7;
    int ie = g * 8 + il;
    const float4* rb = (const float4*)rois + (size_t)b * PCNT;
    const float4* pb = (const float4*)ps + (size_t)b * PCNT;
    float4 r = rb[ie];
    float areaA = (r.z - r.x) * (r.w - r.y);
    int c0 = seedsCnt[b*3+0], a0 = seedsAmax[b*3+0];
    int c1 = seedsCnt[b*3+1], a1 = seedsAmax[b*3+1];
    int c2 = seedsCnt[b*3+2], a2 = seedsAmax[b*3+2];

    unsigned long long best0 = 0, best1 = 0, best2 = 0;
    for (int e = jl; e < PCNT; e += 8) {
        float4 q = rb[e];
        float4 pv = pb[e];
        bool m0 = (c0 <= 1) ? (e == a0) : (pv.x > 0.5f);
        bool m1 = (c1 <= 1) ? (e == a1) : (pv.y > 0.5f);
        bool m2 = (c2 <= 1) ? (e == a2) : (pv.z > 0.5f);
        float lx = fmaxf(r.x, q.x), ly = fmaxf(r.y, q.y);
        float rx = fminf(r.z, q.z), ry = fminf(r.w, q.w);
        float ww = fmaxf(rx - lx, 0.f);
        float hh = fmaxf(ry - ly, 0.f);
        float inter = ww * hh;
        float areaB = (q.z - q.x) * (q.w - q.y);
        float u = (areaA + areaB) - inter;
        float ioup1 = fmaf(inter, __builtin_amdgcn_rcpf(u), 1.0f);
        float iour = ioup1 - 1.0f;
        unsigned lo = 0x7FFFFFFFu - (unsigned)e;
        float t0 = m0 ? iour : 0.f;
        float t1 = m1 ? iour : 0.f;
        float t2 = m2 ? iour : 0.f;
        unsigned long long k0 = ((unsigned long long)(unsigned)__float_as_int(t0) << 32) | lo;
        unsigned long long k1 = ((unsigned long long)(unsigned)__float_as_int(t1) << 32) | lo;
        unsigned long long k2 = ((unsigned long long)(unsigned)__float_as_int(t2) << 32) | lo;
        if (k0 > best0) best0 = k0;
        if (k1 > best1) best1 = k1;
        if (k2 > best2) best2 = k2;
    }
#pragma unroll
    for (int off = 1; off < 8; off <<= 1) {
        unsigned long long o;
        o = __shfl_xor(best0, off, 64); if (o > best0) best0 = o;
        o = __shfl_xor(best1, off, 64); if (o > best1) best1 = o;
        o = __shfl_xor(best2, off, 64); if (o > best2) best2 = o;
    }
    if (jl == 0) {
        size_t kb = ((size_t)b * PCNT + ie) * 3;
        if ((unsigned)(best0 >> 32) >= 0x3F000000u) atomicMax(&keys[kb + 0], best0);
        if ((unsigned)(best1 >> 32) >= 0x3F000000u) atomicMax(&keys[kb + 1], best1);
        if ((unsigned)(best2 >> 32) >= 0x3F000000u) atomicMax(&keys[kb + 2], best2);
    }
}

// ------------------------------------------------------------------
// K3: finalize (thread/row) + per-class partials + last-block loss.
// (R12-proven)
// ------------------------------------------------------------------
__global__ __launch_bounds__(256) void k_finalize_loss(
    const unsigned long long* __restrict__ keys, const float* __restrict__ ps,
    const float* __restrict__ labels, const float* __restrict__ logit,
    float* __restrict__ partials, unsigned* __restrict__ doneCnt,
    float* __restrict__ out_loss, int rows, float invB)
{
    int tid = threadIdx.x;
    int row = blockIdx.x * 256 + tid;
    float vals[8] = {0.f, 0.f, 0.f, 0.f, 0.f, 0.f, 0.f, 0.f};
    if (row < rows) {
        int b = row >> 11;
        float I = -1.f; int cls = 3; float wv = 1.f;
#pragma unroll
        for (int c = 0; c < 3; ++c) {
            unsigned long long key = keys[(size_t)row * 3 + c];
            float lab = labels[b * 4 + c];
            if (key != 0ull && lab > 0.f) {
                float t = __uint_as_float((unsigned)(key >> 32));
                if (t >= 0.5f && t > I) {
                    int j = 0x7FFFFFFF - (int)(key & 0xFFFFFFFFull);
                    I = t; cls = c;
                    wv = ps[((size_t)b * PCNT + j) * 4 + c];
                }
            }
        }
        float4 lg = ((const float4*)logit)[row];
        float l = (cls == 0) ? lg.x : (cls == 1) ? lg.y : (cls == 2) ? lg.z : lg.w;
        float p = fminf(fmaxf(l, 1e-7f), 1.f - 1e-7f);
        float om = 1.f - p;
        float fl = -logf(p) * om * om;
        float lab = (cls == 3) ? 1.f : labels[b * 4 + cls];
        float wu = 10.f * expf(l) * (1.f - lab) + lab;
        float contrib = wv * fl * wu;
        vals[0] = (cls == 0) ? contrib : 0.f; vals[4] = (cls == 0) ? 1.f : 0.f;
        vals[1] = (cls == 1) ? contrib : 0.f; vals[5] = (cls == 1) ? 1.f : 0.f;
        vals[2] = (cls == 2) ? contrib : 0.f; vals[6] = (cls == 2) ? 1.f : 0.f;
        vals[3] = (cls == 3) ? contrib : 0.f; vals[7] = (cls == 3) ? 1.f : 0.f;
    }
#pragma unroll
    for (int comp = 0; comp < 8; ++comp) {
#pragma unroll
        for (int off = 1; off < 64; off <<= 1)
            vals[comp] += __shfl_xor(vals[comp], off, 64);
    }
    __shared__ float wred[4][8];
    __shared__ bool lastBlk;
    int lane = tid & 63, wave = tid >> 6;
    if (lane == 0) {
#pragma unroll
        for (int comp = 0; comp < 8; ++comp) wred[wave][comp] = vals[comp];
    }
    __syncthreads();
    if (tid < 8) {
        partials[blockIdx.x * 8 + tid] =
            wred[0][tid] + wred[1][tid] + wred[2][tid] + wred[3][tid];
        __threadfence();
    }
    __syncthreads();
    if (tid == 0) {
        unsigned old = atomicAdd(doneCnt, 1u);
        lastBlk = (old == gridDim.x - 1);
    }
    __syncthreads();
    if (lastBlk) {
        __threadfence();
        __shared__ float red8[8][32];
        int c = tid & 7, i = tid >> 3;
        float s = 0.f;
        for (int kb = i; kb < (int)gridDim.x; kb += 32) s += partials[kb * 8 + c];
        red8[c][i] = s;
        __syncthreads();
        for (int st = 16; st > 0; st >>= 1) {
            if (i < st) red8[c][i] += red8[c][i + st];
            __syncthreads();
        }
        if (tid == 0) {
            float loss = 0.f;
#pragma unroll
            for (int cc = 0; cc < 4; ++cc)
                loss += red8[cc][0] / (red8[cc + 4][0] + 1e-7f);
            *out_loss = loss * invB;
        }
    }
}

extern "C" void kernel_launch(void* const* d_in, const int* in_sizes, int n_in,
                              void* d_out, int out_size, void* d_ws, size_t ws_size,
                              hipStream_t stream)
{
    const float* inputs = (const float*)d_in[0];
    const float* ps     = (const float*)d_in[1];
    const float* labels = (const float*)d_in[2];
    const float* rois   = (const float*)d_in[3];
    const float* fcw    = (const float*)d_in[4];
    const float* fcb    = (const float*)d_in[5];

    int B = in_sizes[2] / 4;            // 16
    int rows = B * PCNT;                // 32768
    float* out = (float*)d_out;

    char* ws = (char*)d_ws;
    size_t off = 0;
    unsigned long long* keys = (unsigned long long*)(ws + off);
    int nkeys = rows * 3;
    off += (size_t)nkeys * 8;
    off = (off + 255) & ~(size_t)255;
    float* partials = (float*)(ws + off);               off += 128 * 8 * 4;
    unsigned* doneCnt = (unsigned*)(ws + off);          off += 64;
    int* seedsCnt  = (int*)(ws + off);                  off += (size_t)B * 3 * 4;
    int* seedsAmax = (int*)(ws + off);                  off += (size_t)B * 3 * 4;
    off = (off + 255) & ~(size_t)255;
    int* cellCnt   = (int*)(ws + off);                  off += (size_t)B * 64 * 4;
    off = (off + 255) & ~(size_t)255;
    float4* roisE = (float4*)(ws + off);                off += (size_t)B * CAP_B * 16;
    unsigned* metaU = (unsigned*)(ws + off);            off += (size_t)B * CAP_B * 4;
    bool binned = (ws_size >= off);

    int gemvBlocks = rows / 16;   // 2048
    const int NBLK = 128;         // rows/256
    if (binned) {
        int sb = 8 * B;   // 128 scatter blocks, bid 0..sb-1 (scheduled first)
        k_front<<<sb + gemvBlocks, 256, 0, stream>>>(
            inputs, fcw, fcb, out, ps, rois, keys, nkeys,
            cellCnt, roisE, metaU, doneCnt, sb, B);
        k_assign5<<<B * 128, 256, 0, stream>>>(cellCnt, roisE, metaU, keys);
    } else {
        k_front<<<gemvBlocks, 256, 0, stream>>>(
            inputs, fcw, fcb, out, ps, rois, keys, nkeys,
            cellCnt, roisE, metaU, doneCnt, 0, B);
        k_seeds<<<B * 3, 256, 0, stream>>>(ps, seedsCnt, seedsAmax);
        k_assign_fallback<<<B * 64, 256, 0, stream>>>(rois, ps, seedsCnt, seedsAmax, keys);
    }
    k_finalize_loss<<<NBLK, 256, 0, stream>>>(keys, ps, labels, out, partials,
                                              doneCnt, out + (size_t)rows * 4,
                                              rows, 1.f / (float)B);
}